// Round 2
// baseline (2647.236 us; speedup 1.0000x reference)
//
#include <hip/hip_runtime.h>

// CMDNet (M=2, m={-1,+1}, equal alpha).
// Block = 256 threads = 4 waves; each wave independently handles 2 batches.
// lane = h*32 + k (h = batch-half within wave, k = symbol 0..31).
// Per lane: HH row k (32 f32 regs), state {G0,G1,ft0,ft1,xt}.
// No __syncthreads anywhere: every LDS region is private to one wave, and
// within-wave ds_write -> ds_read is ordered by in-order issue + lgkmcnt.
// Softmax over M=2 with equal alpha == sigmoid(tau*(G1-G0)) (exact).
// grad_x * r = +/- 2*tau*ft0*ft1*r  (since 1-xt = 2*ft0, -1-xt = -2*ft1).

#define NRX 64
#define KSYM 32

__device__ __forceinline__ float readlane_f(float v, int lane) {
    return __int_as_float(__builtin_amdgcn_readlane(__float_as_int(v), lane));
}

__global__ __launch_bounds__(256, 8) void cmdnet_kernel(
    const float* __restrict__ yt,      // [B,64]
    const float* __restrict__ Ht,      // [B,64,32]
    const float* __restrict__ sigmat0, // [B]
    const float* __restrict__ taui,    // [niter+1]
    const float* __restrict__ delta,   // [niter]
    float* __restrict__ out_ft,        // [B,32,2]
    float* __restrict__ out_xt,        // [B,32]
    int niter)
{
    __shared__ __align__(16) float HtC[4][2][16][KSYM];  // 16 KB: per-wave staging chunk
    __shared__ __align__(16) float ytL[4][2][NRX];       // 2 KB
    __shared__ __align__(16) float xtL[4][2][KSYM];      // 1 KB

    const int tid  = threadIdx.x;
    const int w    = tid >> 6;         // wave id 0..3
    const int lane = tid & 63;
    const int k    = lane & 31;
    const int h    = lane >> 5;
    const int bb   = blockIdx.x * 8 + w * 2;  // first batch of this wave
    const int b    = bb + h;

    // stage yt for this wave's 2 batches (within-wave LDS, no barrier needed)
    ytL[w][0][lane] = yt[(size_t)bb * NRX + lane];
    ytL[w][1][lane] = yt[(size_t)bb * NRX + NRX + lane];

    // per-lane copies of delta / |taui[1..]|; broadcast later via v_readlane
    float dreg = 0.f, treg = 1.f;
    if (lane < niter) { dreg = delta[lane]; treg = fabsf(taui[lane + 1]); }

    float sig2 = sigmat0[b];
    sig2 *= sig2;

    float hh[KSYM];
    #pragma unroll
    for (int i = 0; i < KSYM; ++i) hh[i] = 0.f;
    float yh = 0.f;

    const float4* HtG = reinterpret_cast<const float4*>(Ht) + (size_t)bb * 512;

    // ---- HH = Ht^T Ht (row k per lane) and yH, streamed in 16-row chunks ----
    for (int c = 0; c < 4; ++c) {
        #pragma unroll
        for (int r = 0; r < 4; ++r) {
            int idx = r * 64 + lane;       // 0..255 float4s this chunk
            int bs  = idx >> 7;            // which of the wave's 2 batches
            int wi  = idx & 127;           // float4 within batch chunk
            float4 v = HtG[(size_t)bs * 512 + c * 128 + wi];
            reinterpret_cast<float4*>(&HtC[w][bs][0][0])[wi] = v;
        }
        #pragma unroll
        for (int n = 0; n < 16; ++n) {
            float a = HtC[w][h][n][k];                    // 2-way aliased (free)
            yh = fmaf(ytL[w][h][c * 16 + n], a, yh);
            const float4* row = reinterpret_cast<const float4*>(&HtC[w][h][n][0]);
            #pragma unroll
            for (int t = 0; t < 8; ++t) {
                float4 rv = row[t];                       // broadcast read
                hh[t*4+0] = fmaf(a, rv.x, hh[t*4+0]);
                hh[t*4+1] = fmaf(a, rv.y, hh[t*4+1]);
                hh[t*4+2] = fmaf(a, rv.z, hh[t*4+2]);
                hh[t*4+3] = fmaf(a, rv.w, hh[t*4+3]);
            }
        }
    }

    // ---- initial state: G=0, tau=|taui[0]| -> softmax(0,0)=0.5, xt=0 (exact) ----
    float tau = fabsf(taui[0]);
    float G0 = 0.f, G1 = 0.f;
    float ft0 = 0.5f, ft1 = 0.5f, xt = 0.f;

    // ---- iterations (no barriers: xtL exchange is within-wave) ----
    for (int i = 0; i < niter; ++i) {
        xtL[w][h][k] = xt;

        float d        = readlane_f(dreg, i);
        float tau_next = readlane_f(treg, i);

        // xHH[k] = sum_l HH[k][l] * xt[l]  (4 independent chains)
        float acc0 = 0.f, acc1 = 0.f, acc2 = 0.f, acc3 = 0.f;
        const float4* xv = reinterpret_cast<const float4*>(&xtL[w][h][0]);
        #pragma unroll
        for (int t = 0; t < 8; t += 4) {
            float4 xa = xv[t+0], xb = xv[t+1], xc = xv[t+2], xd = xv[t+3];
            acc0 = fmaf(hh[t*4+ 0], xa.x, acc0); acc0 = fmaf(hh[t*4+ 1], xa.y, acc0);
            acc0 = fmaf(hh[t*4+ 2], xa.z, acc0); acc0 = fmaf(hh[t*4+ 3], xa.w, acc0);
            acc1 = fmaf(hh[t*4+ 4], xb.x, acc1); acc1 = fmaf(hh[t*4+ 5], xb.y, acc1);
            acc1 = fmaf(hh[t*4+ 6], xb.z, acc1); acc1 = fmaf(hh[t*4+ 7], xb.w, acc1);
            acc2 = fmaf(hh[t*4+ 8], xc.x, acc2); acc2 = fmaf(hh[t*4+ 9], xc.y, acc2);
            acc2 = fmaf(hh[t*4+10], xc.z, acc2); acc2 = fmaf(hh[t*4+11], xc.w, acc2);
            acc3 = fmaf(hh[t*4+12], xd.x, acc3); acc3 = fmaf(hh[t*4+13], xd.y, acc3);
            acc3 = fmaf(hh[t*4+14], xd.z, acc3); acc3 = fmaf(hh[t*4+15], xd.w, acc3);
        }
        float r = ((acc0 + acc1) + (acc2 + acc3)) - yh;

        float p  = 2.f * tau * ft0 * ft1 * r;
        float e0 = __expf(-G0);
        float e1 = __expf(-G1);
        float g0 = fmaf(sig2, 1.f - e0, -p);
        float g1 = fmaf(sig2, 1.f - e1,  p);
        G0 = fmaf(-d, g0, G0);
        G1 = fmaf(-d, g1, G1);

        tau = tau_next;
        float z  = tau * (G1 - G0);
        float ez = __expf(-fabsf(z));
        float s  = __builtin_amdgcn_rcpf(1.f + ez);
        float abig = s, asml = ez * s;
        bool pos = (z >= 0.f);
        ft1 = pos ? abig : asml;
        ft0 = pos ? asml : abig;
        xt  = ft1 - ft0;
    }

    // ---- outputs ----
    float2 f2 = make_float2(ft0, ft1);
    reinterpret_cast<float2*>(out_ft)[(size_t)b * KSYM + k] = f2;
    out_xt[(size_t)b * KSYM + k] = xt;
}

extern "C" void kernel_launch(void* const* d_in, const int* in_sizes, int n_in,
                              void* d_out, int out_size, void* d_ws, size_t ws_size,
                              hipStream_t stream) {
    const float* yt    = (const float*)d_in[0];
    const float* Ht    = (const float*)d_in[1];
    const float* sg    = (const float*)d_in[2];
    const float* taui  = (const float*)d_in[3];
    const float* delta = (const float*)d_in[4];
    int B     = in_sizes[2];
    int niter = in_sizes[4];
    float* out    = (float*)d_out;
    float* out_ft = out;
    float* out_xt = out + (size_t)B * 64;

    dim3 grid(B / 8), block(256);
    hipLaunchKernelGGL(cmdnet_kernel, grid, block, 0, stream,
                       yt, Ht, sg, taui, delta, out_ft, out_xt, niter);
}

// Round 3
// 2220.688 us; speedup vs baseline: 1.1921x; 1.1921x over previous
//
#include <hip/hip_runtime.h>

// CMDNet (M=2, m={-1,+1}, equal alpha).
// Block = 256 threads = 4 waves; each wave independently handles 2 batches.
// lane = h*32 + k (h = batch-half within wave, k = symbol 0..31).
// Per lane: HH row k (32 f32 regs), state {G0,G1,ft0,ft1,xt}.
// No __syncthreads anywhere: every LDS region is private to one wave.
// __launch_bounds__(256, 6): VGPR cap ~85 — R2's (256,8) capped at 64 and
// spilled hh[] to scratch (4.3 GB of scratch traffic, 27x slowdown).
// Softmax over M=2 with equal alpha == sigmoid(tau*(G1-G0)) (exact).
// grad_x * r = +/- 2*tau*ft0*ft1*r  (since 1-xt = 2*ft0, -1-xt = -2*ft1).

#define NRX 64
#define KSYM 32

__device__ __forceinline__ float readlane_f(float v, int lane) {
    return __int_as_float(__builtin_amdgcn_readlane(__float_as_int(v), lane));
}

__global__ __launch_bounds__(256, 6) void cmdnet_kernel(
    const float* __restrict__ yt,      // [B,64]
    const float* __restrict__ Ht,      // [B,64,32]
    const float* __restrict__ sigmat0, // [B]
    const float* __restrict__ taui,    // [niter+1]
    const float* __restrict__ delta,   // [niter]
    float* __restrict__ out_ft,        // [B,32,2]
    float* __restrict__ out_xt,        // [B,32]
    int niter)
{
    __shared__ __align__(16) float HtC[4][2][16][KSYM];  // 16 KB: per-wave staging chunk
    __shared__ __align__(16) float ytL[4][2][NRX];       // 2 KB
    __shared__ __align__(16) float xtL[4][2][KSYM];      // 1 KB

    const int tid  = threadIdx.x;
    const int w    = tid >> 6;         // wave id 0..3
    const int lane = tid & 63;
    const int k    = lane & 31;
    const int h    = lane >> 5;
    const int bb   = blockIdx.x * 8 + w * 2;  // first batch of this wave
    const int b    = bb + h;

    // stage yt for this wave's 2 batches (within-wave LDS, no barrier needed)
    ytL[w][0][lane] = yt[(size_t)bb * NRX + lane];
    ytL[w][1][lane] = yt[(size_t)bb * NRX + NRX + lane];

    // per-lane copies of delta / |taui[1..]|; broadcast later via v_readlane
    float dreg = 0.f, treg = 1.f;
    if (lane < niter) { dreg = delta[lane]; treg = fabsf(taui[lane + 1]); }

    float sig2 = sigmat0[b];
    sig2 *= sig2;

    float hh[KSYM];
    #pragma unroll
    for (int i = 0; i < KSYM; ++i) hh[i] = 0.f;
    float yh = 0.f;

    const float4* HtG = reinterpret_cast<const float4*>(Ht) + (size_t)bb * 512;

    // ---- HH = Ht^T Ht (row k per lane) and yH, streamed in 16-row chunks ----
    for (int c = 0; c < 4; ++c) {
        #pragma unroll
        for (int r = 0; r < 4; ++r) {
            int idx = r * 64 + lane;       // 0..255 float4s this chunk
            int bs  = idx >> 7;            // which of the wave's 2 batches
            int wi  = idx & 127;           // float4 within batch chunk
            float4 v = HtG[(size_t)bs * 512 + c * 128 + wi];
            reinterpret_cast<float4*>(&HtC[w][bs][0][0])[wi] = v;
        }
        #pragma unroll
        for (int n = 0; n < 16; ++n) {
            float a = HtC[w][h][n][k];                    // 2-way aliased (free)
            yh = fmaf(ytL[w][h][c * 16 + n], a, yh);
            const float4* row = reinterpret_cast<const float4*>(&HtC[w][h][n][0]);
            #pragma unroll
            for (int t = 0; t < 8; ++t) {
                float4 rv = row[t];                       // broadcast read
                hh[t*4+0] = fmaf(a, rv.x, hh[t*4+0]);
                hh[t*4+1] = fmaf(a, rv.y, hh[t*4+1]);
                hh[t*4+2] = fmaf(a, rv.z, hh[t*4+2]);
                hh[t*4+3] = fmaf(a, rv.w, hh[t*4+3]);
            }
        }
    }

    // ---- initial state: G=0, tau=|taui[0]| -> softmax(0,0)=0.5, xt=0 (exact) ----
    float tau = fabsf(taui[0]);
    float G0 = 0.f, G1 = 0.f;
    float ft0 = 0.5f, ft1 = 0.5f, xt = 0.f;

    // ---- iterations (no barriers: xtL exchange is within-wave) ----
    for (int i = 0; i < niter; ++i) {
        xtL[w][h][k] = xt;

        float d        = readlane_f(dreg, i);
        float tau_next = readlane_f(treg, i);

        // xHH[k] = sum_l HH[k][l] * xt[l]  (4 independent chains)
        float acc0 = 0.f, acc1 = 0.f, acc2 = 0.f, acc3 = 0.f;
        const float4* xv = reinterpret_cast<const float4*>(&xtL[w][h][0]);
        #pragma unroll
        for (int t = 0; t < 8; t += 4) {
            float4 xa = xv[t+0], xb = xv[t+1], xc = xv[t+2], xd = xv[t+3];
            acc0 = fmaf(hh[t*4+ 0], xa.x, acc0); acc0 = fmaf(hh[t*4+ 1], xa.y, acc0);
            acc0 = fmaf(hh[t*4+ 2], xa.z, acc0); acc0 = fmaf(hh[t*4+ 3], xa.w, acc0);
            acc1 = fmaf(hh[t*4+ 4], xb.x, acc1); acc1 = fmaf(hh[t*4+ 5], xb.y, acc1);
            acc1 = fmaf(hh[t*4+ 6], xb.z, acc1); acc1 = fmaf(hh[t*4+ 7], xb.w, acc1);
            acc2 = fmaf(hh[t*4+ 8], xc.x, acc2); acc2 = fmaf(hh[t*4+ 9], xc.y, acc2);
            acc2 = fmaf(hh[t*4+10], xc.z, acc2); acc2 = fmaf(hh[t*4+11], xc.w, acc2);
            acc3 = fmaf(hh[t*4+12], xd.x, acc3); acc3 = fmaf(hh[t*4+13], xd.y, acc3);
            acc3 = fmaf(hh[t*4+14], xd.z, acc3); acc3 = fmaf(hh[t*4+15], xd.w, acc3);
        }
        float r = ((acc0 + acc1) + (acc2 + acc3)) - yh;

        float p  = 2.f * tau * ft0 * ft1 * r;
        float e0 = __expf(-G0);
        float e1 = __expf(-G1);
        float g0 = fmaf(sig2, 1.f - e0, -p);
        float g1 = fmaf(sig2, 1.f - e1,  p);
        G0 = fmaf(-d, g0, G0);
        G1 = fmaf(-d, g1, G1);

        tau = tau_next;
        float z  = tau * (G1 - G0);
        float ez = __expf(-fabsf(z));
        float s  = __builtin_amdgcn_rcpf(1.f + ez);
        float abig = s, asml = ez * s;
        bool pos = (z >= 0.f);
        ft1 = pos ? abig : asml;
        ft0 = pos ? asml : abig;
        xt  = ft1 - ft0;
    }

    // ---- outputs ----
    float2 f2 = make_float2(ft0, ft1);
    reinterpret_cast<float2*>(out_ft)[(size_t)b * KSYM + k] = f2;
    out_xt[(size_t)b * KSYM + k] = xt;
}

extern "C" void kernel_launch(void* const* d_in, const int* in_sizes, int n_in,
                              void* d_out, int out_size, void* d_ws, size_t ws_size,
                              hipStream_t stream) {
    const float* yt    = (const float*)d_in[0];
    const float* Ht    = (const float*)d_in[1];
    const float* sg    = (const float*)d_in[2];
    const float* taui  = (const float*)d_in[3];
    const float* delta = (const float*)d_in[4];
    int B     = in_sizes[2];
    int niter = in_sizes[4];
    float* out    = (float*)d_out;
    float* out_ft = out;
    float* out_xt = out + (size_t)B * 64;

    dim3 grid(B / 8), block(256);
    hipLaunchKernelGGL(cmdnet_kernel, grid, block, 0, stream,
                       yt, Ht, sg, taui, delta, out_ft, out_xt, niter);
}

// Round 4
// 90.002 us; speedup vs baseline: 29.4130x; 24.6737x over previous
//
#include <hip/hip_runtime.h>

// CMDNet (M=2, m={-1,+1}, equal alpha) — MFMA HH edition.
// Block = 256 threads = 4 waves, barrier-free; each wave owns 2 batches.
// lane = h*32 + k (h = batch-half, k = symbol).
//
// Phase 1: HH = Ht^T Ht per batch via v_mfma_f32_32x32x16_bf16 with bf16
//   hi/lo split (Hhi'Hhi + Hhi'Hlo + Hlo'Hhi; lo*lo dropped, err ~2^-17).
//   Same regs fed as A and B => any consistent k-slot permutation cancels.
//   yH accumulated as VALU partials on the same loaded values.
// Phase 2: redistribute D (C/D layout: col=lane&31, row=(j&3)+8*(j>>2)+4*(lane>>5),
//   verified m74/m101) so lane (h,k) holds full HH_h[k][*] via shfl_xor(32):
//   own[j]=HH[4h + (j&3)+8*(j>>2)][k], oth[j]=HH[4(1-h) + ...][k].
// Phase 3: 64 iterations; xt exchanged through LDS in MFMA-row order
//   (pos(k) = ((k>>2)&1)*16 + (k&3) + 4*(k>>3)) so reads are linear b128.
//
// __launch_bounds__(256,4): VGPR cap 128. R2/R3 lesson: gfx950 occupancy
// steps at 64/128/256 VGPRs; asking >4 waves/EU forces <=64 regs and spills
// (R2/R3: 4+ GB scratch traffic). 128-cap = 4 waves/SIMD, no spill.

#define NRX 64
#define KSYM 32

typedef float  f32x16 __attribute__((ext_vector_type(16)));
typedef short  short8 __attribute__((ext_vector_type(8)));

__device__ __forceinline__ float readlane_f(float v, int lane) {
    return __int_as_float(__builtin_amdgcn_readlane(__float_as_int(v), lane));
}
__device__ __forceinline__ unsigned cvt_pk_bf16(float a, float b) {
    unsigned r;
    asm("v_cvt_pk_bf16_f32 %0, %1, %2" : "=v"(r) : "v"(a), "v"(b));
    return r;   // low16 = bf16(a), high16 = bf16(b), RNE
}

union FragU { unsigned u[4]; short8 s; };

__global__ __launch_bounds__(256, 4) void cmdnet_kernel(
    const float* __restrict__ yt,      // [B,64]
    const float* __restrict__ Ht,      // [B,64,32]
    const float* __restrict__ sigmat0, // [B]
    const float* __restrict__ taui,    // [niter+1]
    const float* __restrict__ delta,   // [niter]
    float* __restrict__ out_ft,        // [B,32,2]
    float* __restrict__ out_xt,        // [B,32]
    int niter)
{
    __shared__ __align__(16) float ytL[4][2][NRX];   // 2 KB
    __shared__ __align__(16) float xtP[4][2][KSYM];  // 1 KB, MFMA-row order

    const int tid  = threadIdx.x;
    const int w    = tid >> 6;
    const int lane = tid & 63;
    const int k    = lane & 31;
    const int h    = lane >> 5;
    const int hi8  = h * 8;                 // n-offset of this half-wave's frag rows
    const int bb   = blockIdx.x * 8 + w * 2;
    const int b    = bb + h;

    // stage yt for the wave's 2 batches (within-wave LDS: no barrier needed)
    ytL[w][0][lane] = yt[(size_t)bb * NRX + lane];
    ytL[w][1][lane] = yt[(size_t)bb * NRX + NRX + lane];

    float dreg = 0.f, treg = 1.f;
    if (lane < niter) { dreg = delta[lane]; treg = fabsf(taui[lane + 1]); }

    float sig2 = sigmat0[b];
    sig2 *= sig2;

    // ---- Phase 1: MFMA HH (+ yH VALU partials) ----
    f32x16 acc0, acc1;
    #pragma unroll
    for (int j = 0; j < 16; ++j) { acc0[j] = 0.f; acc1[j] = 0.f; }
    float yhp0 = 0.f, yhp1 = 0.f;

    #pragma unroll
    for (int s = 0; s < 2; ++s) {
        const float* Hb = Ht + ((size_t)(bb + s)) * (NRX * KSYM);
        #pragma unroll
        for (int c = 0; c < 4; ++c) {
            const float* base = Hb + (c * 16 + hi8) * KSYM + k;
            float f[8];
            #pragma unroll
            for (int e = 0; e < 8; ++e) f[e] = base[e * KSYM];  // 2x128B segments, coalesced

            // yH partials: y[c*16+hi8+e] * H[n][k]
            float4 ya = *reinterpret_cast<const float4*>(&ytL[w][s][c * 16 + hi8]);
            float4 yb = *reinterpret_cast<const float4*>(&ytL[w][s][c * 16 + hi8 + 4]);
            float yp = (s == 0) ? yhp0 : yhp1;
            yp = fmaf(ya.x, f[0], yp); yp = fmaf(ya.y, f[1], yp);
            yp = fmaf(ya.z, f[2], yp); yp = fmaf(ya.w, f[3], yp);
            yp = fmaf(yb.x, f[4], yp); yp = fmaf(yb.y, f[5], yp);
            yp = fmaf(yb.z, f[6], yp); yp = fmaf(yb.w, f[7], yp);
            if (s == 0) yhp0 = yp; else yhp1 = yp;

            // bf16 hi/lo split
            FragU hiF, loF;
            #pragma unroll
            for (int p = 0; p < 4; ++p) {
                unsigned hp = cvt_pk_bf16(f[2*p], f[2*p+1]);
                float h0 = __uint_as_float(hp << 16);
                float h1 = __uint_as_float(hp & 0xffff0000u);
                float l0 = f[2*p]   - h0;
                float l1 = f[2*p+1] - h1;
                hiF.u[p] = hp;
                loF.u[p] = cvt_pk_bf16(l0, l1);
            }
            if (s == 0) {
                acc0 = __builtin_amdgcn_mfma_f32_32x32x16_bf16(hiF.s, hiF.s, acc0, 0, 0, 0);
                acc0 = __builtin_amdgcn_mfma_f32_32x32x16_bf16(hiF.s, loF.s, acc0, 0, 0, 0);
                acc0 = __builtin_amdgcn_mfma_f32_32x32x16_bf16(loF.s, hiF.s, acc0, 0, 0, 0);
            } else {
                acc1 = __builtin_amdgcn_mfma_f32_32x32x16_bf16(hiF.s, hiF.s, acc1, 0, 0, 0);
                acc1 = __builtin_amdgcn_mfma_f32_32x32x16_bf16(hiF.s, loF.s, acc1, 0, 0, 0);
                acc1 = __builtin_amdgcn_mfma_f32_32x32x16_bf16(loF.s, hiF.s, acc1, 0, 0, 0);
            }
        }
    }

    // finish yH: each lane has half the n-range; partner (lane^32) has the rest
    float yh0 = yhp0 + __shfl_xor(yhp0, 32, 64);
    float yh1 = yhp1 + __shfl_xor(yhp1, 32, 64);
    float yh  = h ? yh1 : yh0;

    // ---- Phase 2: redistribute HH so lane (h,k) holds full row k of batch h ----
    // own[j] = HH_h[(j&3)+8*(j>>2)+4*h][k]      (own regs of own-batch acc)
    // oth[j] = HH_h[(j&3)+8*(j>>2)+4*(1-h)][k]  (partner lane's own-batch acc)
    float own[16], oth[16];
    #pragma unroll
    for (int j = 0; j < 16; ++j) {
        float t = h ? acc1[j] : acc0[j];   // own batch, own row-group
        float u = h ? acc0[j] : acc1[j];   // other batch (partner wants it)
        own[j] = t;
        oth[j] = __shfl_xor(u, 32, 64);
    }

    // ---- Phase 3: iterations ----
    float tau = fabsf(taui[0]);
    float G0 = 0.f, G1 = 0.f;
    float ft0 = 0.5f, ft1 = 0.5f, xt = 0.f;

    const int pos = ((k >> 2) & 1) * 16 + (k & 3) + ((k >> 3) << 2);
    const float4* xo = reinterpret_cast<const float4*>(&xtP[w][h][h * 16]);
    const float4* xx = reinterpret_cast<const float4*>(&xtP[w][h][(1 ^ h) * 16]);

    for (int i = 0; i < niter; ++i) {
        xtP[w][h][pos] = xt;

        float d        = readlane_f(dreg, i);
        float tau_next = readlane_f(treg, i);

        float a0 = 0.f, a1 = 0.f, a2 = 0.f, a3 = 0.f;
        #pragma unroll
        for (int t = 0; t < 4; ++t) {
            float4 xa = xo[t];
            float4 xb = xx[t];
            float aco = (t & 1) ? 0.f : 0.f; // (kept simple; 4 chains below)
            (void)aco;
            a0 = fmaf(own[4*t+0], xa.x, a0);
            a1 = fmaf(own[4*t+1], xa.y, a1);
            a2 = fmaf(own[4*t+2], xa.z, a2);
            a3 = fmaf(own[4*t+3], xa.w, a3);
            a0 = fmaf(oth[4*t+0], xb.x, a0);
            a1 = fmaf(oth[4*t+1], xb.y, a1);
            a2 = fmaf(oth[4*t+2], xb.z, a2);
            a3 = fmaf(oth[4*t+3], xb.w, a3);
        }
        float r = ((a0 + a1) + (a2 + a3)) - yh;

        float p  = 2.f * tau * ft0 * ft1 * r;
        float e0 = __expf(-G0);
        float e1 = __expf(-G1);
        float g0 = fmaf(sig2, 1.f - e0, -p);
        float g1 = fmaf(sig2, 1.f - e1,  p);
        G0 = fmaf(-d, g0, G0);
        G1 = fmaf(-d, g1, G1);

        tau = tau_next;
        float z  = tau * (G1 - G0);
        float ez = __expf(-fabsf(z));
        float sg = __builtin_amdgcn_rcpf(1.f + ez);
        float abig = sg, asml = ez * sg;
        bool ps = (z >= 0.f);
        ft1 = ps ? abig : asml;
        ft0 = ps ? asml : abig;
        xt  = ft1 - ft0;
    }

    // ---- outputs ----
    float2 f2 = make_float2(ft0, ft1);
    reinterpret_cast<float2*>(out_ft)[(size_t)b * KSYM + k] = f2;
    out_xt[(size_t)b * KSYM + k] = xt;
}

extern "C" void kernel_launch(void* const* d_in, const int* in_sizes, int n_in,
                              void* d_out, int out_size, void* d_ws, size_t ws_size,
                              hipStream_t stream) {
    const float* yt    = (const float*)d_in[0];
    const float* Ht    = (const float*)d_in[1];
    const float* sg    = (const float*)d_in[2];
    const float* taui  = (const float*)d_in[3];
    const float* delta = (const float*)d_in[4];
    int B     = in_sizes[2];
    int niter = in_sizes[4];
    float* out    = (float*)d_out;
    float* out_ft = out;
    float* out_xt = out + (size_t)B * 64;

    dim3 grid(B / 8), block(256);
    hipLaunchKernelGGL(cmdnet_kernel, grid, block, 0, stream,
                       yt, Ht, sg, taui, delta, out_ft, out_xt, niter);
}